// Round 1
// baseline (949.982 us; speedup 1.0000x reference)
//
#include <hip/hip_runtime.h>
#include <hip/hip_bf16.h>

// Problem: N=8192 rows, D=1024, H=4096, 5 affine blocks B(v)=v*M+c with
// M = fc1_W^T @ fc2_W^T  (collapses H=4096 out of the per-stage GEMMs).
// Outputs: inv_total [8192,1024], nxt = x - inv_total [8192,1024], loss [1024,1024]
// loss rows are identical: loss[a,b] = Dtot[b].

#define NR 8192
#define DD 1024
#define HH 4096
#define NL 5

using bf16 = __hip_bfloat16;
typedef __attribute__((ext_vector_type(8))) short bf16x8;
typedef __attribute__((ext_vector_type(4))) float f32x4;

// ---------------- conversion / transpose ----------------

__global__ void cvt_bf16_kernel(const float* __restrict__ in, bf16* __restrict__ out, int n4) {
  int i = blockIdx.x * 256 + threadIdx.x;
  int stride = gridDim.x * 256;
  union U { bf16 b[4]; uint2 u; };
  for (; i < n4; i += stride) {
    float4 v = ((const float4*)in)[i];
    U u;
    u.b[0] = __float2bfloat16(v.x); u.b[1] = __float2bfloat16(v.y);
    u.b[2] = __float2bfloat16(v.z); u.b[3] = __float2bfloat16(v.w);
    ((uint2*)out)[i] = u.u;
  }
}

// fc1_W [4096][1024] f32 -> fc1T_bf [1024][4096] bf16
__global__ void transpose_cvt_kernel(const float* __restrict__ in, bf16* __restrict__ out) {
  __shared__ bf16 tile[64][74];   // pitch 74 elem -> bank stride 37 dwords (odd): conflict-free
  int c0 = blockIdx.x * 64;       // input col tile base (0..1023)
  int r0 = blockIdx.y * 64;       // input row tile base (0..4095)
  int col = threadIdx.x & 63;
  int row4 = threadIdx.x >> 6;    // 0..3
  #pragma unroll
  for (int j = 0; j < 16; ++j) {
    int r = row4 * 16 + j;
    tile[r][col] = __float2bfloat16(in[(size_t)(r0 + r) * DD + c0 + col]);
  }
  __syncthreads();
  #pragma unroll
  for (int j = 0; j < 16; ++j) {
    int r = row4 * 16 + j;        // output row within tile (= input col)
    out[(size_t)(c0 + r) * HH + r0 + col] = tile[col][r];
  }
}

// c[j] = sum_k fc1_b[k] * fc2_W[j][k] + fc2_b[j]   (fp32, exact path)
__global__ void cvec_kernel(const float* __restrict__ fc1_b, const float* __restrict__ fc2_W,
                            const float* __restrict__ fc2_b, float* __restrict__ c) {
  int j = blockIdx.x;
  float s = 0.f;
  for (int k = threadIdx.x; k < HH; k += 256) s += fc1_b[k] * fc2_W[(size_t)j * HH + k];
  for (int o = 32; o; o >>= 1) s += __shfl_down(s, o);
  __shared__ float red[4];
  if ((threadIdx.x & 63) == 0) red[threadIdx.x >> 6] = s;
  __syncthreads();
  if (threadIdx.x == 0) c[j] = red[0] + red[1] + red[2] + red[3] + fc2_b[j];
}

__global__ void zero_kernel(float* __restrict__ p, int n) {
  int i = blockIdx.x * 256 + threadIdx.x;
  if (i < n) p[i] = 0.f;
}

// ---------------- GEMM: C[m,n] = sum_k A[m,k]*B[n,k]  (both K-contiguous) ----------------
// MODE 0: write bf16 C^T to p3 (MT production)
// MODE 1: stage epilogue: v=acc+bias[n]; invtot(p0) +=/=; nxtf(p1) -=/= x(p2)-v;
//         p3 = bf16(nxt) [next-stage A operand], p4 = bf16(v) [loss GEMM A operand]
// MODE 2: ph[m,n] = fp16(acc + bias[n])

#define BM 128
#define BN 128
#define BKT 64
#define LDT 72   // padded LDS pitch (elements): 144B rows -> 2-way (free) bank aliasing

template<int MODE>
__global__ __launch_bounds__(256, 2)
void gemm_bt(const bf16* __restrict__ A, const bf16* __restrict__ B,
             int M, int N, int K, int lda, int ldb,
             const float* __restrict__ bias,
             float* __restrict__ p0, float* __restrict__ p1,
             const float* __restrict__ p2,
             bf16* __restrict__ p3, bf16* __restrict__ p4,
             _Float16* __restrict__ ph, int first)
{
  __shared__ bf16 As[BM * LDT];
  __shared__ bf16 Bs[BN * LDT];
  const int tid  = threadIdx.x;
  const int lane = tid & 63;
  const int wave = tid >> 6;
  const int wm = (wave & 1) * 64;
  const int wn = (wave >> 1) * 64;
  const int bm = blockIdx.y * BM;
  const int bn = blockIdx.x * BN;

  f32x4 acc[4][4] = {};

  const int srow = tid >> 3;        // 0..31
  const int scol = (tid & 7) * 8;   // element col within BK tile

  for (int k0 = 0; k0 < K; k0 += BKT) {
    #pragma unroll
    for (int it = 0; it < 4; ++it) {
      int r = srow + it * 32;
      *(uint4*)(&As[r * LDT + scol]) = *(const uint4*)(A + (size_t)(bm + r) * lda + k0 + scol);
      *(uint4*)(&Bs[r * LDT + scol]) = *(const uint4*)(B + (size_t)(bn + r) * ldb + k0 + scol);
    }
    __syncthreads();
    #pragma unroll
    for (int ks = 0; ks < 2; ++ks) {
      const int kk = ks * 32 + (lane >> 4) * 8;
      bf16x8 av[4], bv[4];
      #pragma unroll
      for (int i = 0; i < 4; ++i) {
        av[i] = *(const bf16x8*)(&As[(wm + i * 16 + (lane & 15)) * LDT + kk]);
        bv[i] = *(const bf16x8*)(&Bs[(wn + i * 16 + (lane & 15)) * LDT + kk]);
      }
      #pragma unroll
      for (int i = 0; i < 4; ++i)
        #pragma unroll
        for (int j = 0; j < 4; ++j)
          acc[i][j] = __builtin_amdgcn_mfma_f32_16x16x32_bf16(av[i], bv[j], acc[i][j], 0, 0, 0);
    }
    __syncthreads();
  }

  // epilogue: C row = bm+wm+i*16+(lane>>4)*4+r ; col = bn+wn+j*16+(lane&15)
  #pragma unroll
  for (int i = 0; i < 4; ++i) {
    #pragma unroll
    for (int j = 0; j < 4; ++j) {
      const int col = bn + wn + j * 16 + (lane & 15);
      float bj = 0.f;
      if constexpr (MODE != 0) bj = bias[col];
      #pragma unroll
      for (int r = 0; r < 4; ++r) {
        const int row = bm + wm + i * 16 + (lane >> 4) * 4 + r;
        const float v = acc[i][j][r] + bj;
        if constexpr (MODE == 0) {
          p3[(size_t)col * M + row] = __float2bfloat16(v);   // C^T
        } else if constexpr (MODE == 1) {
          const size_t idx = (size_t)row * N + col;
          float it, nf;
          if (first) { it = v; nf = p2[idx] - v; }
          else       { it = p0[idx] + v; nf = p1[idx] - v; }
          p0[idx] = it;
          p1[idx] = nf;
          p3[idx] = __float2bfloat16(nf);
          p4[idx] = __float2bfloat16(v);
        } else {
          ph[(size_t)row * N + col] = (_Float16)v;
        }
      }
    }
  }
}

// ---------------- loss reductions ----------------

// one block per (layer,row): S = sum(out), n2 = ||out||
__global__ void rowstats_kernel(const _Float16* __restrict__ oh,
                                float* __restrict__ Srow, float* __restrict__ Nrow) {
  int rid = blockIdx.x;                       // z*8192 + n
  const _Float16* p = oh + (size_t)rid * DD;
  float s = 0.f, q = 0.f;
  for (int k = threadIdx.x; k < DD; k += 256) { float v = (float)p[k]; s += v; q += v * v; }
  for (int o = 32; o; o >>= 1) { s += __shfl_down(s, o); q += __shfl_down(q, o); }
  __shared__ float rs[4], rq[4];
  if ((threadIdx.x & 63) == 0) { rs[threadIdx.x >> 6] = s; rq[threadIdx.x >> 6] = q; }
  __syncthreads();
  if (threadIdx.x == 0) {
    Srow[rid] = rs[0] + rs[1] + rs[2] + rs[3];
    Nrow[rid] = sqrtf(rq[0] + rq[1] + rq[2] + rq[3]);
  }
}

// Dtot[j] += sum over layer z, rows n of |c[n+1,j]-c[n,j]|,
// c = out*S / max(|out|*32*n2, 1e-8)   (sqrt(1024)=32)
#define LC_ROWS 512
__global__ void losscol_kernel(const _Float16* __restrict__ oh, const float* __restrict__ Srow,
                               const float* __restrict__ Nrow, float* __restrict__ Dtot) {
  const int z = blockIdx.z;
  const int j = blockIdx.x * 256 + threadIdx.x;
  const int n0 = blockIdx.y * LC_ROWS;
  int nend = n0 + LC_ROWS; if (nend > NR - 1) nend = NR - 1;
  const _Float16* base = oh + (size_t)z * NR * DD;
  const float* S = Srow + z * NR;
  const float* Nn = Nrow + z * NR;
  auto cval = [&](int n) {
    float ov = (float)base[(size_t)n * DD + j];
    float denom = fmaxf(fabsf(ov) * 32.0f * Nn[n], 1e-8f);
    return ov * S[n] / denom;
  };
  float prev = cval(n0), d = 0.f;
  for (int n = n0 + 1; n <= nend; ++n) {
    float cv = cval(n);
    d += fabsf(cv - prev);
    prev = cv;
  }
  atomicAdd(&Dtot[j], d);
}

__global__ void writeloss_kernel(const float* __restrict__ Dtot, float* __restrict__ out) {
  int idx = blockIdx.x * 256 + threadIdx.x;   // 0..1048575
  out[idx] = Dtot[idx & (DD - 1)];
}

// ---------------- launch ----------------

extern "C" void kernel_launch(void* const* d_in, const int* in_sizes, int n_in,
                              void* d_out, int out_size, void* d_ws, size_t ws_size,
                              hipStream_t stream) {
  const float* x      = (const float*)d_in[0];
  const float* fc1_W  = (const float*)d_in[1];
  const float* fc1_b  = (const float*)d_in[2];
  const float* fc2_W  = (const float*)d_in[3];
  const float* fc2_b  = (const float*)d_in[4];
  const float* comp_W = (const float*)d_in[5];
  const float* comp_b = (const float*)d_in[6];

  float* invtot  = (float*)d_out;                        // [8192,1024]
  float* nxtf    = invtot + (size_t)NR * DD;             // [8192,1024]
  float* lossout = invtot + (size_t)2 * NR * DD;         // [1024,1024]

  char* w = (char*)d_ws;
  auto alloc = [&](size_t bytes) { char* p = w; w += (bytes + 255) & ~(size_t)255; return p; };
  bf16* x_bf     = (bf16*)alloc((size_t)NR * DD * 2);        // 16 MB
  bf16* fc1T_bf  = (bf16*)alloc((size_t)DD * HH * 2);        // 8 MB
  bf16* fc2_bf   = (bf16*)alloc((size_t)DD * HH * 2);        // 8 MB
  bf16* compW_bf = (bf16*)alloc((size_t)NL * DD * DD * 2);   // 10 MB
  bf16* MT_bf    = (bf16*)alloc((size_t)DD * DD * 2);        // 2 MB
  bf16* nxt_bf0  = (bf16*)alloc((size_t)NR * DD * 2);        // 16 MB (double-buffered:
  bf16* nxt_bf1  = (bf16*)alloc((size_t)NR * DD * 2);        // 16 MB  in-place A-operand hazard)
  bf16* inv_bf   = (bf16*)alloc((size_t)NR * DD * 2);        // 16 MB
  _Float16* out_h= (_Float16*)alloc((size_t)NL * NR * DD * 2); // 80 MB
  float* cvec = (float*)alloc(DD * 4);
  float* Srow = (float*)alloc((size_t)NL * NR * 4);
  float* Nrow = (float*)alloc((size_t)NL * NR * 4);
  float* Dtot = (float*)alloc(DD * 4);
  (void)ws_size; (void)in_sizes; (void)n_in; (void)out_size;

  // conversions
  cvt_bf16_kernel<<<2048, 256, 0, stream>>>(x, x_bf, NR * DD / 4);
  cvt_bf16_kernel<<<1024, 256, 0, stream>>>(fc2_W, fc2_bf, DD * HH / 4);
  cvt_bf16_kernel<<<1024, 256, 0, stream>>>(comp_W, compW_bf, NL * DD * DD / 4);
  transpose_cvt_kernel<<<dim3(DD / 64, HH / 64), 256, 0, stream>>>(fc1_W, fc1T_bf);
  cvec_kernel<<<DD, 256, 0, stream>>>(fc1_b, fc2_W, fc2_b, cvec);
  zero_kernel<<<4, 256, 0, stream>>>(Dtot, DD);

  // M = fc1_W^T @ fc2_W^T  -> stored transposed (MT[n,k] = M[k,n]) as bf16
  gemm_bt<0><<<dim3(DD / BN, DD / BM), 256, 0, stream>>>(
      fc1T_bf, fc2_bf, DD, DD, HH, HH, HH,
      nullptr, nullptr, nullptr, nullptr, MT_bf, nullptr, nullptr, 0);

  // 5 stages: inv_i = nxt_{i-1} @ M + c ; invtot += inv_i ; nxt -= inv_i
  for (int i = 0; i < NL; ++i) {
    const bf16* Aop = (i == 0) ? x_bf : ((i & 1) ? nxt_bf0 : nxt_bf1);
    bf16* nxt_out   = (i & 1) ? nxt_bf1 : nxt_bf0;
    gemm_bt<1><<<dim3(DD / BN, NR / BM), 256, 0, stream>>>(
        Aop, MT_bf, NR, DD, DD, DD, DD,
        cvec, invtot, nxtf, x, nxt_out, inv_bf, nullptr, i == 0 ? 1 : 0);
    // out_i = inv_i @ comp_W[i]^T + comp_b[i] -> fp16
    gemm_bt<2><<<dim3(DD / BN, NR / BM), 256, 0, stream>>>(
        inv_bf, compW_bf + (size_t)i * DD * DD, NR, DD, DD, DD, DD,
        comp_b + (size_t)i * DD, nullptr, nullptr, nullptr, nullptr, nullptr,
        out_h + (size_t)i * NR * DD, 0);
  }

  // loss: row stats then column |diff| accumulation, then rank-1 broadcast
  rowstats_kernel<<<NL * NR, 256, 0, stream>>>(out_h, Srow, Nrow);
  losscol_kernel<<<dim3(DD / 256, NR / LC_ROWS, NL), 256, 0, stream>>>(out_h, Srow, Nrow, Dtot);
  writeloss_kernel<<<DD * DD / 256, 256, 0, stream>>>(Dtot, lossout);
}

// Round 2
// 634.913 us; speedup vs baseline: 1.4962x; 1.4962x over previous
//
#include <hip/hip_runtime.h>
#include <hip/hip_bf16.h>

// Affine collapse: B(v)=v*M+c with M = fc1_W^T @ fc2_W^T, T = I-M.
//   inv_i      = x*T^{i-1}M + c*T^{i-1}
//   inv_total  = x*(S*M) + c*S,  S = I+T+T^2+T^3+T^4
//   nxt        = x - inv_total
//   out_i      = x*Bout_i + f_i,  Bout_i = T^{i-1}*(M*compW_i^T), f_i = c*T^{i-1}*compW_i^T + b_i
// One main GEMM [8192 x 6144 x 1024] computes invtot + all five out_i.
// loss[a,b] = Dtot[b] (rank-1).

#define NR 8192
#define DD 1024
#define HH 4096
#define NL 5
#define MSZ (DD * DD)

using bf16 = __hip_bfloat16;
typedef __attribute__((ext_vector_type(8))) short bf16x8;
typedef __attribute__((ext_vector_type(4))) float f32x4;
typedef _Float16 h4 __attribute__((ext_vector_type(4)));

// ---------------- conversions / elementwise ----------------

__global__ void cvt_bf16_kernel(const float* __restrict__ in, bf16* __restrict__ out, int n4) {
  int i = blockIdx.x * 256 + threadIdx.x;
  int stride = gridDim.x * 256;
  union U { bf16 b[4]; uint2 u; };
  for (; i < n4; i += stride) {
    float4 v = ((const float4*)in)[i];
    U u;
    u.b[0] = __float2bfloat16(v.x); u.b[1] = __float2bfloat16(v.y);
    u.b[2] = __float2bfloat16(v.z); u.b[3] = __float2bfloat16(v.w);
    ((uint2*)out)[i] = u.u;
  }
}

// fc1_W [4096][1024] f32 -> fc1T_bf [1024][4096] bf16
__global__ void transpose_cvt_kernel(const float* __restrict__ in, bf16* __restrict__ out) {
  __shared__ bf16 tile[64][74];
  int c0 = blockIdx.x * 64;
  int r0 = blockIdx.y * 64;
  int col = threadIdx.x & 63;
  int row4 = threadIdx.x >> 6;
  #pragma unroll
  for (int j = 0; j < 16; ++j) {
    int r = row4 * 16 + j;
    tile[r][col] = __float2bfloat16(in[(size_t)(r0 + r) * DD + c0 + col]);
  }
  __syncthreads();
  #pragma unroll
  for (int j = 0; j < 16; ++j) {
    int r = row4 * 16 + j;
    out[(size_t)(c0 + r) * HH + r0 + col] = tile[col][r];
  }
}

// c[j] = sum_k fc1_b[k]*fc2_W[j][k] + fc2_b[j]
__global__ void cvec_kernel(const float* __restrict__ fc1_b, const float* __restrict__ fc2_W,
                            const float* __restrict__ fc2_b, float* __restrict__ c) {
  int j = blockIdx.x;
  float s = 0.f;
  for (int k = threadIdx.x; k < HH; k += 256) s += fc1_b[k] * fc2_W[(size_t)j * HH + k];
  for (int o = 32; o; o >>= 1) s += __shfl_down(s, o);
  __shared__ float red[4];
  if ((threadIdx.x & 63) == 0) red[threadIdx.x >> 6] = s;
  __syncthreads();
  if (threadIdx.x == 0) c[j] = red[0] + red[1] + red[2] + red[3] + fc2_b[j];
}

__global__ void zero_kernel(float* __restrict__ p, int n) {
  int i = blockIdx.x * 256 + threadIdx.x;
  if (i < n) p[i] = 0.f;
}

// T = I - M (normal and transposed layouts)
__global__ void tbuild_kernel(const bf16* __restrict__ M, const bf16* __restrict__ Mt,
                              bf16* __restrict__ T, bf16* __restrict__ Tt) {
  int idx = blockIdx.x * 256 + threadIdx.x;
  int m = idx >> 10, n = idx & (DD - 1);
  float d = (m == n) ? 1.f : 0.f;
  T[idx]  = __float2bfloat16(d - __bfloat162float(M[idx]));
  Tt[idx] = __float2bfloat16(d - __bfloat162float(Mt[idx]));
}

// S = I + T + T2 + T3 + T4  (Pw = [T,T2,T3,T4] contiguous)
__global__ void sbuild_kernel(const bf16* __restrict__ Pw, bf16* __restrict__ S) {
  int idx = blockIdx.x * 256 + threadIdx.x;
  int m = idx >> 10, n = idx & (DD - 1);
  float v = (m == n) ? 1.f : 0.f;
  v += __bfloat162float(Pw[idx]) + __bfloat162float(Pw[MSZ + idx])
     + __bfloat162float(Pw[2 * MSZ + idx]) + __bfloat162float(Pw[3 * MSZ + idx]);
  S[idx] = __float2bfloat16(v);
}

// out[z*DD+j] = sum_k v[k] * Bt[z][j][k]   (row-vector times matrix, Bt = transposed matrix)
__global__ void vecmat_kernel(const float* __restrict__ v, const bf16* __restrict__ Bt,
                              float* __restrict__ out) {
  int z = blockIdx.y, j = blockIdx.x;
  const bf16* row = Bt + (size_t)z * MSZ + (size_t)j * DD;
  float s = 0.f;
  for (int k = threadIdx.x; k < DD; k += 256) s += v[k] * __bfloat162float(row[k]);
  for (int o = 32; o; o >>= 1) s += __shfl_down(s, o);
  __shared__ float red[4];
  if ((threadIdx.x & 63) == 0) red[threadIdx.x >> 6] = s;
  __syncthreads();
  if (threadIdx.x == 0) out[(size_t)z * DD + j] = red[0] + red[1] + red[2] + red[3];
}

// biasall[0..1023] = g = c+e2+e3+e4+e5 ; biasall[z*1024+j] = e_z . compW_z^T + b_z (z=1..5)
__global__ void biasall_kernel(const float* __restrict__ cvec, const float* __restrict__ ebuf,
                               const float* __restrict__ comp_W, const float* __restrict__ comp_b,
                               float* __restrict__ biasall) {
  int z = blockIdx.y, j = blockIdx.x;
  if (z == 0) {
    if (threadIdx.x == 0)
      biasall[j] = cvec[j] + ebuf[j] + ebuf[DD + j] + ebuf[2 * DD + j] + ebuf[3 * DD + j];
    return;
  }
  int i = z - 1;
  const float* e = (i == 0) ? cvec : ebuf + (size_t)(i - 1) * DD;
  const float* wr = comp_W + (size_t)i * MSZ + (size_t)j * DD;
  float s = 0.f;
  for (int k = threadIdx.x; k < DD; k += 256) s += e[k] * wr[k];
  for (int o = 32; o; o >>= 1) s += __shfl_down(s, o);
  __shared__ float red[4];
  if ((threadIdx.x & 63) == 0) red[threadIdx.x >> 6] = s;
  __syncthreads();
  if (threadIdx.x == 0)
    biasall[(size_t)z * DD + j] = red[0] + red[1] + red[2] + red[3] + comp_b[(size_t)i * DD + j];
}

// ---------------- GEMM core: C[m,n] = sum_k A[m,k]*B[n,k] ----------------

#define BM 128
#define BN 128
#define BKT 64
#define LDT 72   // padded LDS pitch: 2-way bank aliasing only (free)

__device__ __forceinline__ void gemm_core(const bf16* __restrict__ A, const bf16* __restrict__ B,
                                          int K, int lda, int ldb, int bm, int bn,
                                          bf16* As, bf16* Bs, f32x4 acc[4][4]) {
  const int tid  = threadIdx.x;
  const int lane = tid & 63;
  const int wm = ((tid >> 6) & 1) * 64;
  const int wn = ((tid >> 6) >> 1) * 64;
  const int srow = tid >> 3;
  const int scol = (tid & 7) * 8;

  for (int k0 = 0; k0 < K; k0 += BKT) {
    #pragma unroll
    for (int it = 0; it < 4; ++it) {
      int r = srow + it * 32;
      *(uint4*)(&As[r * LDT + scol]) = *(const uint4*)(A + (size_t)(bm + r) * lda + k0 + scol);
      *(uint4*)(&Bs[r * LDT + scol]) = *(const uint4*)(B + (size_t)(bn + r) * ldb + k0 + scol);
    }
    __syncthreads();
    #pragma unroll
    for (int ks = 0; ks < 2; ++ks) {
      const int kk = ks * 32 + (lane >> 4) * 8;
      bf16x8 av[4], bv[4];
      #pragma unroll
      for (int i = 0; i < 4; ++i) {
        av[i] = *(const bf16x8*)(&As[(wm + i * 16 + (lane & 15)) * LDT + kk]);
        bv[i] = *(const bf16x8*)(&Bs[(wn + i * 16 + (lane & 15)) * LDT + kk]);
      }
      #pragma unroll
      for (int i = 0; i < 4; ++i)
        #pragma unroll
        for (int j = 0; j < 4; ++j)
          acc[i][j] = __builtin_amdgcn_mfma_f32_16x16x32_bf16(av[i], bv[j], acc[i][j], 0, 0, 0);
    }
    __syncthreads();
  }
}

// dual-output: Cn[row*DD+col] and Ct[col*DD+row], both bf16 (M=N=1024)
__global__ __launch_bounds__(256, 2)
void gemm_dual(const bf16* __restrict__ A, const bf16* __restrict__ B, int K, int lda, int ldb,
               bf16* __restrict__ Ct, bf16* __restrict__ Cn) {
  __shared__ bf16 As[BM * LDT];
  __shared__ bf16 Bs[BN * LDT];
  f32x4 acc[4][4] = {};
  const int bm = blockIdx.y * BM, bn = blockIdx.x * BN;
  gemm_core(A, B, K, lda, ldb, bm, bn, As, Bs, acc);
  const int lane = threadIdx.x & 63;
  const int wm = ((threadIdx.x >> 6) & 1) * 64, wn = ((threadIdx.x >> 6) >> 1) * 64;
  #pragma unroll
  for (int i = 0; i < 4; ++i)
    #pragma unroll
    for (int j = 0; j < 4; ++j) {
      const int col = bn + wn + j * 16 + (lane & 15);
      #pragma unroll
      for (int r = 0; r < 4; ++r) {
        const int row = bm + wm + i * 16 + (lane >> 4) * 4 + r;
        bf16 v = __float2bfloat16(acc[i][j][r]);
        Cn[(size_t)row * DD + col] = v;
        Ct[(size_t)col * DD + row] = v;
      }
    }
}

// batched normal-output 1024^3 GEMM; z>=zswitch uses override pointers (z-zswitch==0 case)
__global__ __launch_bounds__(256, 2)
void gemm_b4(const bf16* __restrict__ A0, long astr, const bf16* __restrict__ B0, long bstr,
             bf16* __restrict__ C0, long cstr,
             const bf16* __restrict__ A2, const bf16* __restrict__ B2, bf16* __restrict__ C2,
             int zswitch) {
  __shared__ bf16 As[BM * LDT];
  __shared__ bf16 Bs[BN * LDT];
  const int z = blockIdx.z;
  const bf16* A; const bf16* B; bf16* C;
  if (z < zswitch) { A = A0 + (size_t)z * astr; B = B0 + (size_t)z * bstr; C = C0 + (size_t)z * cstr; }
  else             { A = A2; B = B2; C = C2; }
  f32x4 acc[4][4] = {};
  const int bm = blockIdx.y * BM, bn = blockIdx.x * BN;
  gemm_core(A, B, DD, DD, DD, bm, bn, As, Bs, acc);
  const int lane = threadIdx.x & 63;
  const int wm = ((threadIdx.x >> 6) & 1) * 64, wn = ((threadIdx.x >> 6) >> 1) * 64;
  #pragma unroll
  for (int i = 0; i < 4; ++i)
    #pragma unroll
    for (int j = 0; j < 4; ++j) {
      const int col = bn + wn + j * 16 + (lane & 15);
      #pragma unroll
      for (int r = 0; r < 4; ++r) {
        const int row = bm + wm + i * 16 + (lane >> 4) * 4 + r;
        C[(size_t)row * DD + col] = __float2bfloat16(acc[i][j][r]);
      }
    }
}

// main GEMM [8192 x 6144 x 1024]: cols 0..1023 -> invtot/nxt, cols 1024+ -> out_z (fp16)
// + fused per-row S (sum) and Q (sum of squares) via butterfly + atomics
__global__ __launch_bounds__(256, 2)
void gemm_main(const bf16* __restrict__ A, const bf16* __restrict__ Bb,
               const float* __restrict__ biasall, const float* __restrict__ x,
               float* __restrict__ invtot, float* __restrict__ nxtf,
               _Float16* __restrict__ out_h, float* __restrict__ Srow, float* __restrict__ Qrow) {
  __shared__ bf16 As[BM * LDT];
  __shared__ bf16 Bs[BN * LDT];
  f32x4 acc[4][4] = {};
  const int bm = blockIdx.y * BM, bn = blockIdx.x * BN;
  gemm_core(A, Bb, DD, DD, DD, bm, bn, As, Bs, acc);
  const int lane = threadIdx.x & 63;
  const int wm = ((threadIdx.x >> 6) & 1) * 64, wn = ((threadIdx.x >> 6) >> 1) * 64;

  if (bn < DD) {
    #pragma unroll
    for (int i = 0; i < 4; ++i)
      #pragma unroll
      for (int j = 0; j < 4; ++j) {
        const int col = bn + wn + j * 16 + (lane & 15);
        const float bj = biasall[col];
        #pragma unroll
        for (int r = 0; r < 4; ++r) {
          const int row = bm + wm + i * 16 + (lane >> 4) * 4 + r;
          const float v = acc[i][j][r] + bj;
          const size_t idx = (size_t)row * DD + col;
          invtot[idx] = v;
          nxtf[idx] = x[idx] - v;
        }
      }
  } else {
    const int z = (bn >> 10) - 1;
    _Float16* oz = out_h + (size_t)z * NR * DD;
    const int cbase = bn & (DD - 1);
    float sv[4][4] = {}, qv[4][4] = {};
    #pragma unroll
    for (int i = 0; i < 4; ++i)
      #pragma unroll
      for (int j = 0; j < 4; ++j) {
        const int colg = bn + wn + j * 16 + (lane & 15);
        const int cj = cbase + wn + j * 16 + (lane & 15);
        const float bj = biasall[colg];
        #pragma unroll
        for (int r = 0; r < 4; ++r) {
          const int row = bm + wm + i * 16 + (lane >> 4) * 4 + r;
          const float v = acc[i][j][r] + bj;
          oz[(size_t)row * DD + cj] = (_Float16)v;
          sv[i][r] += v;
          qv[i][r] += v * v;
        }
      }
    #pragma unroll
    for (int i = 0; i < 4; ++i)
      #pragma unroll
      for (int r = 0; r < 4; ++r) {
        float s = sv[i][r], q = qv[i][r];
        #pragma unroll
        for (int off = 1; off < 16; off <<= 1) { s += __shfl_xor(s, off); q += __shfl_xor(q, off); }
        if ((lane & 15) == 0) {
          const int row = bm + wm + i * 16 + (lane >> 4) * 4 + r;
          atomicAdd(&Srow[(size_t)z * NR + row], s);
          atomicAdd(&Qrow[(size_t)z * NR + row], q);
        }
      }
  }
}

// ---------------- loss ----------------

// Dtot[j] += sum_z sum_n |c[n+1,j]-c[n,j]| ; c = ov*S/max(|ov|*32*sqrt(Q),1e-8)
#define LCR 64
__global__ void losscol2_kernel(const _Float16* __restrict__ oh, const float* __restrict__ Srow,
                                const float* __restrict__ Qrow, float* __restrict__ Dtot) {
  const int z = blockIdx.y;
  const int n0 = blockIdx.x * LCR;
  int nend = n0 + LCR; if (nend > NR - 1) nend = NR - 1;   // pairs n..n+1, n in [n0, nend)
  const _Float16* base = oh + (size_t)z * NR * DD + (size_t)threadIdx.x * 4;
  const float* S = Srow + (size_t)z * NR;
  const float* Q = Qrow + (size_t)z * NR;
  float c[4], d[4] = {0.f, 0.f, 0.f, 0.f};
  auto compute = [&](int n, float* cv) {
    h4 o = *(const h4*)(base + (size_t)n * DD);
    float s = S[n];
    float t = 32.0f * sqrtf(Q[n]);
    #pragma unroll
    for (int k = 0; k < 4; ++k) {
      float ov = (float)o[k];
      cv[k] = ov * s / fmaxf(fabsf(ov) * t, 1e-8f);
    }
  };
  compute(n0, c);
  for (int n = n0 + 1; n <= nend; ++n) {
    float cn[4];
    compute(n, cn);
    #pragma unroll
    for (int k = 0; k < 4; ++k) { d[k] += fabsf(cn[k] - c[k]); c[k] = cn[k]; }
  }
  #pragma unroll
  for (int k = 0; k < 4; ++k) atomicAdd(&Dtot[threadIdx.x * 4 + k], d[k]);
}

__global__ void writeloss_kernel(const float* __restrict__ Dtot, float* __restrict__ out) {
  int idx = blockIdx.x * 256 + threadIdx.x;
  out[idx] = Dtot[idx & (DD - 1)];
}

// ---------------- launch ----------------

extern "C" void kernel_launch(void* const* d_in, const int* in_sizes, int n_in,
                              void* d_out, int out_size, void* d_ws, size_t ws_size,
                              hipStream_t stream) {
  const float* x      = (const float*)d_in[0];
  const float* fc1_W  = (const float*)d_in[1];
  const float* fc1_b  = (const float*)d_in[2];
  const float* fc2_W  = (const float*)d_in[3];
  const float* fc2_b  = (const float*)d_in[4];
  const float* comp_W = (const float*)d_in[5];
  const float* comp_b = (const float*)d_in[6];

  float* invtot  = (float*)d_out;
  float* nxtf    = invtot + (size_t)NR * DD;
  float* lossout = invtot + (size_t)2 * NR * DD;

  char* w = (char*)d_ws;
  auto alloc = [&](size_t bytes) { char* p = w; w += (bytes + 255) & ~(size_t)255; return p; };
  bf16* x_bf     = (bf16*)alloc((size_t)NR * DD * 2);          // 16 MB
  bf16* fc1T_bf  = (bf16*)alloc((size_t)DD * HH * 2);          // 8 MB
  bf16* fc2_bf   = (bf16*)alloc((size_t)DD * HH * 2);          // 8 MB
  bf16* compW_bf = (bf16*)alloc((size_t)NL * MSZ * 2);         // 10 MB
  bf16* M_bf     = (bf16*)alloc((size_t)MSZ * 2);              // 2 MB
  bf16* Mt_bf    = (bf16*)alloc((size_t)MSZ * 2);              // 2 MB
  bf16* Tt_buf   = (bf16*)alloc((size_t)2 * MSZ * 2);          // [Tt, T2t] 4 MB
  bf16* Pw       = (bf16*)alloc((size_t)4 * MSZ * 2);          // [T, T2, T3, T4] 8 MB
  bf16* S_bf     = (bf16*)alloc((size_t)MSZ * 2);              // 2 MB
  bf16* Gt       = (bf16*)alloc((size_t)NL * MSZ * 2);         // G_i^T, 10 MB
  bf16* Bbig     = (bf16*)alloc((size_t)6 * MSZ * 2);          // [SMt|Bout1t..Bout5t] 12 MB
  _Float16* out_h = (_Float16*)alloc((size_t)NL * NR * DD * 2); // 80 MB
  float* cvec    = (float*)alloc(DD * 4);
  float* ebuf    = (float*)alloc((size_t)4 * DD * 4);          // e2..e5
  float* biasall = (float*)alloc((size_t)6 * DD * 4);
  float* stats   = (float*)alloc((size_t)(DD + 2 * NL * NR) * 4);
  float* Dtot = stats;
  float* Srow = stats + DD;
  float* Qrow = Srow + (size_t)NL * NR;
  (void)ws_size; (void)in_sizes; (void)n_in; (void)out_size;

  // conversions + zeros
  cvt_bf16_kernel<<<2048, 256, 0, stream>>>(x, x_bf, NR * DD / 4);
  cvt_bf16_kernel<<<1024, 256, 0, stream>>>(fc2_W, fc2_bf, DD * HH / 4);
  cvt_bf16_kernel<<<1024, 256, 0, stream>>>(comp_W, compW_bf, NL * MSZ / 4);
  transpose_cvt_kernel<<<dim3(DD / 64, HH / 64), 256, 0, stream>>>(fc1_W, fc1T_bf);
  cvec_kernel<<<DD, 256, 0, stream>>>(fc1_b, fc2_W, fc2_b, cvec);
  zero_kernel<<<(DD + 2 * NL * NR + 255) / 256, 256, 0, stream>>>(stats, DD + 2 * NL * NR);

  // M = fc1^T fc2^T (K=4096), dual layout
  gemm_dual<<<dim3(8, 8), 256, 0, stream>>>(fc1T_bf, fc2_bf, HH, HH, HH, Mt_bf, M_bf);
  // T, Tt
  tbuild_kernel<<<MSZ / 256, 256, 0, stream>>>(M_bf, Mt_bf, Pw, Tt_buf);
  // G_i^T = compW_i * M^T  (batched)
  gemm_b4<<<dim3(8, 8, NL), 256, 0, stream>>>(compW_bf, MSZ, M_bf, 0, Gt, MSZ,
                                              nullptr, nullptr, nullptr, 99);
  // Bout_1^T = G_1^T
  hipMemcpyAsync(Bbig + MSZ, Gt, (size_t)MSZ * 2, hipMemcpyDeviceToDevice, stream);
  // T2 (dual)
  gemm_dual<<<dim3(8, 8), 256, 0, stream>>>(Pw, Tt_buf, DD, DD, DD, Tt_buf + MSZ, Pw + MSZ);
  // T3 = T2*T, T4 = T2*T2 (batched)
  gemm_b4<<<dim3(8, 8, 2), 256, 0, stream>>>(Pw + MSZ, 0, Tt_buf, MSZ, Pw + 2 * MSZ, MSZ,
                                             nullptr, nullptr, nullptr, 99);
  // S = I+T+T2+T3+T4
  sbuild_kernel<<<MSZ / 256, 256, 0, stream>>>(Pw, S_bf);
  // Bout_i^T = G_i^T * (T^{i-1})^T for i=2..5 (z=0..3), plus z=4: SMt = Mt * S^T = (S*M)^T
  gemm_b4<<<dim3(8, 8, NL), 256, 0, stream>>>(Gt + MSZ, MSZ, Pw, MSZ, Bbig + 2 * MSZ, MSZ,
                                              Mt_bf, S_bf, Bbig, 4);
  // bias vectors: e2=c*T, e3=c*T^2 then e4=e3*T, e5=e3*T^2
  vecmat_kernel<<<dim3(DD, 2), 256, 0, stream>>>(cvec, Tt_buf, ebuf);
  vecmat_kernel<<<dim3(DD, 2), 256, 0, stream>>>(ebuf + DD, Tt_buf, ebuf + 2 * DD);
  biasall_kernel<<<dim3(DD, 6), 256, 0, stream>>>(cvec, ebuf, comp_W, comp_b, biasall);

  // main GEMM: everything at once
  gemm_main<<<dim3(6 * DD / BN, NR / BM), 256, 0, stream>>>(
      x_bf, Bbig, biasall, x, invtot, nxtf, out_h, Srow, Qrow);

  // loss
  losscol2_kernel<<<dim3(NR / LCR, NL), 256, 0, stream>>>(out_h, Srow, Qrow, Dtot);
  writeloss_kernel<<<MSZ / 256, 256, 0, stream>>>(Dtot, lossout);
}

// Round 3
// 524.852 us; speedup vs baseline: 1.8100x; 1.2097x over previous
//
#include <hip/hip_runtime.h>
#include <hip/hip_bf16.h>

// Affine collapse: B(v)=v*M+c with M = fc1_W^T @ fc2_W^T, T = I-M.
//   inv_total = x*(S*M) + c*S,  S = I+T+T^2+T^3+T^4 ;  nxt = x - inv_total
//   out_i = x*Bout_i + f_i,  Bout_i = T^{i-1}*(M*compW_i^T)
// One main GEMM [8192 x 6144 x 1024] computes invtot + all five out_i.
// loss[a,b] = Dtot[b] (rank-1).
// GEMM core: m97 structure — global_load_lds width=16 direct-to-LDS staging,
// XOR-swizzled unpadded LDS (2-way bank aliasing only, free per m136).

#define NR 8192
#define DD 1024
#define HH 4096
#define NL 5
#define MSZ (DD * DD)

using bf16 = __hip_bfloat16;
typedef __attribute__((ext_vector_type(8))) short bf16x8;
typedef __attribute__((ext_vector_type(4))) float f32x4;
typedef _Float16 h4 __attribute__((ext_vector_type(4)));

// ---------------- conversions / elementwise ----------------

__global__ void cvt_bf16_kernel(const float* __restrict__ in, bf16* __restrict__ out, int n4) {
  int i = blockIdx.x * 256 + threadIdx.x;
  int stride = gridDim.x * 256;
  union U { bf16 b[4]; uint2 u; };
  for (; i < n4; i += stride) {
    float4 v = ((const float4*)in)[i];
    U u;
    u.b[0] = __float2bfloat16(v.x); u.b[1] = __float2bfloat16(v.y);
    u.b[2] = __float2bfloat16(v.z); u.b[3] = __float2bfloat16(v.w);
    ((uint2*)out)[i] = u.u;
  }
}

// fc1_W [4096][1024] f32 -> fc1T_bf [1024][4096] bf16
__global__ void transpose_cvt_kernel(const float* __restrict__ in, bf16* __restrict__ out) {
  __shared__ bf16 tile[64][74];
  int c0 = blockIdx.x * 64;
  int r0 = blockIdx.y * 64;
  int col = threadIdx.x & 63;
  int row4 = threadIdx.x >> 6;
  #pragma unroll
  for (int j = 0; j < 16; ++j) {
    int r = row4 * 16 + j;
    tile[r][col] = __float2bfloat16(in[(size_t)(r0 + r) * DD + c0 + col]);
  }
  __syncthreads();
  #pragma unroll
  for (int j = 0; j < 16; ++j) {
    int r = row4 * 16 + j;
    out[(size_t)(c0 + r) * HH + r0 + col] = tile[col][r];
  }
}

// c[j] = sum_k fc1_b[k]*fc2_W[j][k] + fc2_b[j]
__global__ void cvec_kernel(const float* __restrict__ fc1_b, const float* __restrict__ fc2_W,
                            const float* __restrict__ fc2_b, float* __restrict__ c) {
  int j = blockIdx.x;
  float s = 0.f;
  for (int k = threadIdx.x; k < HH; k += 256) s += fc1_b[k] * fc2_W[(size_t)j * HH + k];
  for (int o = 32; o; o >>= 1) s += __shfl_down(s, o);
  __shared__ float red[4];
  if ((threadIdx.x & 63) == 0) red[threadIdx.x >> 6] = s;
  __syncthreads();
  if (threadIdx.x == 0) c[j] = red[0] + red[1] + red[2] + red[3] + fc2_b[j];
}

__global__ void zero_kernel(float* __restrict__ p, int n) {
  int i = blockIdx.x * 256 + threadIdx.x;
  if (i < n) p[i] = 0.f;
}

// sum 4 split-K fp32 partials -> M (bf16, normal+transposed) and T=I-M (normal+transposed)
__global__ void mbuild_kernel(const float* __restrict__ Cp,
                              bf16* __restrict__ M, bf16* __restrict__ Mt,
                              bf16* __restrict__ T, bf16* __restrict__ Tt) {
  __shared__ float tile[64][65];
  int n0 = blockIdx.x * 64, m0 = blockIdx.y * 64;
  int tn = threadIdx.x & 63, tm4 = threadIdx.x >> 6;
  #pragma unroll
  for (int j = 0; j < 16; ++j) {
    int m = tm4 * 16 + j;
    size_t idx = (size_t)(m0 + m) * DD + n0 + tn;
    float v = Cp[idx] + Cp[MSZ + idx] + Cp[2 * MSZ + idx] + Cp[3 * MSZ + idx];
    tile[m][tn] = v;
    float d = ((m0 + m) == (n0 + tn)) ? 1.f : 0.f;
    M[idx] = __float2bfloat16(v);
    T[idx] = __float2bfloat16(d - v);
  }
  __syncthreads();
  #pragma unroll
  for (int j = 0; j < 16; ++j) {
    int r = tm4 * 16 + j;
    float v = tile[tn][r];
    size_t idx = (size_t)(n0 + r) * DD + m0 + tn;
    float d = ((n0 + r) == (m0 + tn)) ? 1.f : 0.f;
    Mt[idx] = __float2bfloat16(v);
    Tt[idx] = __float2bfloat16(d - v);
  }
}

// S = I + T + T2 + T3 + T4  (Pw = [T,T2,T3,T4] contiguous)
__global__ void sbuild_kernel(const bf16* __restrict__ Pw, bf16* __restrict__ S) {
  int idx = blockIdx.x * 256 + threadIdx.x;
  int m = idx >> 10, n = idx & (DD - 1);
  float v = (m == n) ? 1.f : 0.f;
  v += __bfloat162float(Pw[idx]) + __bfloat162float(Pw[MSZ + idx])
     + __bfloat162float(Pw[2 * MSZ + idx]) + __bfloat162float(Pw[3 * MSZ + idx]);
  S[idx] = __float2bfloat16(v);
}

// out[z*DD+j] = sum_k v[k] * Bt[z][j][k]
__global__ void vecmat_kernel(const float* __restrict__ v, const bf16* __restrict__ Bt,
                              float* __restrict__ out) {
  int z = blockIdx.y, j = blockIdx.x;
  const bf16* row = Bt + (size_t)z * MSZ + (size_t)j * DD;
  float s = 0.f;
  for (int k = threadIdx.x; k < DD; k += 256) s += v[k] * __bfloat162float(row[k]);
  for (int o = 32; o; o >>= 1) s += __shfl_down(s, o);
  __shared__ float red[4];
  if ((threadIdx.x & 63) == 0) red[threadIdx.x >> 6] = s;
  __syncthreads();
  if (threadIdx.x == 0) out[(size_t)z * DD + j] = red[0] + red[1] + red[2] + red[3];
}

// biasall[0..1023] = c+e2+e3+e4+e5 ; biasall[z*1024+j] = e_z . compW_z^T + b_z (z=1..5)
__global__ void biasall_kernel(const float* __restrict__ cvec, const float* __restrict__ ebuf,
                               const float* __restrict__ comp_W, const float* __restrict__ comp_b,
                               float* __restrict__ biasall) {
  int z = blockIdx.y, j = blockIdx.x;
  if (z == 0) {
    if (threadIdx.x == 0)
      biasall[j] = cvec[j] + ebuf[j] + ebuf[DD + j] + ebuf[2 * DD + j] + ebuf[3 * DD + j];
    return;
  }
  int i = z - 1;
  const float* e = (i == 0) ? cvec : ebuf + (size_t)(i - 1) * DD;
  const float* wr = comp_W + (size_t)i * MSZ + (size_t)j * DD;
  float s = 0.f;
  for (int k = threadIdx.x; k < DD; k += 256) s += e[k] * wr[k];
  for (int o = 32; o; o >>= 1) s += __shfl_down(s, o);
  __shared__ float red[4];
  if ((threadIdx.x & 63) == 0) red[threadIdx.x >> 6] = s;
  __syncthreads();
  if (threadIdx.x == 0)
    biasall[(size_t)z * DD + j] = red[0] + red[1] + red[2] + red[3] + comp_b[(size_t)i * DD + j];
}

// ---------------- async GEMM core: C[m,n] = sum_k A[m,k]*B[n,k] ----------------
// BM=BN=128, BK=64. LDS tiles 128 rows x 64 cols bf16, unpadded (128 B pitch),
// XOR-swizzled: phys_chunk = logical_chunk ^ (row & 7). global_load_lds dest is
// wave-uniform base + lane*16B -> lane covers (row = lane>>3, phys = lane&7),
// so its global source chunk = (lane&7)^(lane>>3): a fixed per-lane offset.

__device__ __forceinline__ void async16(const bf16* g, bf16* l) {
  __builtin_amdgcn_global_load_lds(
      (const __attribute__((address_space(1))) void*)g,
      (__attribute__((address_space(3))) void*)l, 16, 0, 0);
}

__device__ __forceinline__ void gemm_core_async(
    const bf16* __restrict__ A, const bf16* __restrict__ B,
    int kBeg, int kEnd, int lda, int ldb, int bm, int bn,
    bf16* As, bf16* Bs, f32x4 acc[4][4])
{
  const int tid  = threadIdx.x;
  const int lane = tid & 63;
  const int wave = tid >> 6;
  const int wm = (wave & 1) * 64;
  const int wn = (wave >> 1) * 64;
  const int lr = lane >> 3;                 // row within 8-row DMA group
  const int lcol = ((lane & 7) ^ lr) * 8;   // swizzled source chunk
  const bf16* gA = A + (size_t)(bm + wave * 32 + lr) * lda + lcol;
  const bf16* gB = B + (size_t)(bn + wave * 32 + lr) * ldb + lcol;
  bf16* lA = As + wave * 32 * 64;           // wave-uniform LDS bases
  bf16* lB = Bs + wave * 32 * 64;

  for (int k0 = kBeg; k0 < kEnd; k0 += 64) {
    #pragma unroll
    for (int it = 0; it < 4; ++it) {
      async16(gA + (size_t)(it * 8) * lda + k0, lA + it * 8 * 64);
      async16(gB + (size_t)(it * 8) * ldb + k0, lB + it * 8 * 64);
    }
    __syncthreads();   // compiler emits vmcnt(0) drain before barrier
    #pragma unroll
    for (int ks = 0; ks < 2; ++ks) {
      bf16x8 av[4], bv[4];
      #pragma unroll
      for (int i = 0; i < 4; ++i) {
        const int rr = i * 16 + (lane & 15);
        const int cc = ((ks * 4 + (lane >> 4)) ^ (lane & 7)) * 8;  // unswizzle
        av[i] = *(const bf16x8*)(As + (wm + rr) * 64 + cc);
        bv[i] = *(const bf16x8*)(Bs + (wn + rr) * 64 + cc);
      }
      #pragma unroll
      for (int i = 0; i < 4; ++i)
        #pragma unroll
        for (int j = 0; j < 4; ++j)
          acc[i][j] = __builtin_amdgcn_mfma_f32_16x16x32_bf16(av[i], bv[j], acc[i][j], 0, 0, 0);
    }
    __syncthreads();
  }
}

#define GEMM_PROLOGUE \
  alignas(16) __shared__ bf16 As[128 * 64]; \
  alignas(16) __shared__ bf16 Bs[128 * 64]; \
  f32x4 acc[4][4] = {}; \
  const int lane = threadIdx.x & 63; \
  const int wm = ((threadIdx.x >> 6) & 1) * 64; \
  const int wn = ((threadIdx.x >> 6) >> 1) * 64;

// split-K partial GEMM for M = fc1T * fc2 (K=4096 in 4 chunks), fp32 partials
__global__ __launch_bounds__(256, 2)
void gemm_splitk(const bf16* __restrict__ A, const bf16* __restrict__ B, float* __restrict__ Cp) {
  GEMM_PROLOGUE
  const int bm = blockIdx.y * 128, bn = blockIdx.x * 128;
  const int kb = blockIdx.z * (HH / 4);
  gemm_core_async(A, B, kb, kb + HH / 4, HH, HH, bm, bn, As, Bs, acc);
  float* C = Cp + (size_t)blockIdx.z * MSZ;
  #pragma unroll
  for (int i = 0; i < 4; ++i)
    #pragma unroll
    for (int j = 0; j < 4; ++j) {
      const int col = bn + wn + j * 16 + (lane & 15);
      #pragma unroll
      for (int r = 0; r < 4; ++r) {
        const int row = bm + wm + i * 16 + (lane >> 4) * 4 + r;
        C[(size_t)row * DD + col] = acc[i][j][r];
      }
    }
}

// dual-output 1024^3: Cn normal + Ct transposed (packed 8B stores)
__global__ __launch_bounds__(256, 2)
void gemm_dual(const bf16* __restrict__ A, const bf16* __restrict__ B,
               bf16* __restrict__ Ct, bf16* __restrict__ Cn) {
  GEMM_PROLOGUE
  const int bm = blockIdx.y * 128, bn = blockIdx.x * 128;
  gemm_core_async(A, B, 0, DD, DD, DD, bm, bn, As, Bs, acc);
  #pragma unroll
  for (int i = 0; i < 4; ++i)
    #pragma unroll
    for (int j = 0; j < 4; ++j) {
      const int col = bn + wn + j * 16 + (lane & 15);
      const int row0 = bm + wm + i * 16 + (lane >> 4) * 4;
      union { bf16 b[4]; uint2 u; } pk;
      #pragma unroll
      for (int r = 0; r < 4; ++r) {
        bf16 v = __float2bfloat16(acc[i][j][r]);
        pk.b[r] = v;
        Cn[(size_t)(row0 + r) * DD + col] = v;
      }
      *(uint2*)(&Ct[(size_t)col * DD + row0]) = pk.u;
    }
}

// batched 1024^3; z>=zswitch uses override pointers
__global__ __launch_bounds__(256, 2)
void gemm_b4(const bf16* __restrict__ A0, long astr, const bf16* __restrict__ B0, long bstr,
             bf16* __restrict__ C0, long cstr,
             const bf16* __restrict__ A2, const bf16* __restrict__ B2, bf16* __restrict__ C2,
             int zswitch) {
  GEMM_PROLOGUE
  const int z = blockIdx.z;
  const bf16* A; const bf16* B; bf16* C;
  if (z < zswitch) { A = A0 + (size_t)z * astr; B = B0 + (size_t)z * bstr; C = C0 + (size_t)z * cstr; }
  else             { A = A2; B = B2; C = C2; }
  const int bm = blockIdx.y * 128, bn = blockIdx.x * 128;
  gemm_core_async(A, B, 0, DD, DD, DD, bm, bn, As, Bs, acc);
  #pragma unroll
  for (int i = 0; i < 4; ++i)
    #pragma unroll
    for (int j = 0; j < 4; ++j) {
      const int col = bn + wn + j * 16 + (lane & 15);
      #pragma unroll
      for (int r = 0; r < 4; ++r) {
        const int row = bm + wm + i * 16 + (lane >> 4) * 4 + r;
        C[(size_t)row * DD + col] = __float2bfloat16(acc[i][j][r]);
      }
    }
}

// main GEMM [8192 x 6144 x 1024]: cols 0..1023 -> invtot/nxt, cols 1024+ -> out_z (fp16)
// + fused per-row S and Q via butterfly + atomics
__global__ __launch_bounds__(256, 2)
void gemm_main(const bf16* __restrict__ A, const bf16* __restrict__ Bb,
               const float* __restrict__ biasall, const float* __restrict__ x,
               float* __restrict__ invtot, float* __restrict__ nxtf,
               _Float16* __restrict__ out_h, float* __restrict__ Srow, float* __restrict__ Qrow) {
  GEMM_PROLOGUE
  const int bm = blockIdx.y * 128, bn = blockIdx.x * 128;
  gemm_core_async(A, Bb + (size_t)(bn >> 10) * MSZ, 0, DD, DD, DD, bm, bn & (DD - 1), As, Bs, acc);

  if (bn < DD) {
    #pragma unroll
    for (int i = 0; i < 4; ++i)
      #pragma unroll
      for (int j = 0; j < 4; ++j) {
        const int col = bn + wn + j * 16 + (lane & 15);
        const float bj = biasall[col];
        #pragma unroll
        for (int r = 0; r < 4; ++r) {
          const int row = bm + wm + i * 16 + (lane >> 4) * 4 + r;
          const float v = acc[i][j][r] + bj;
          const size_t idx = (size_t)row * DD + col;
          invtot[idx] = v;
          nxtf[idx] = x[idx] - v;
        }
      }
  } else {
    const int z = (bn >> 10) - 1;
    _Float16* oz = out_h + (size_t)z * NR * DD;
    const int cbase = bn & (DD - 1);
    float sv[4][4] = {}, qv[4][4] = {};
    #pragma unroll
    for (int i = 0; i < 4; ++i)
      #pragma unroll
      for (int j = 0; j < 4; ++j) {
        const int colg = bn + wn + j * 16 + (lane & 15);
        const int cj = cbase + wn + j * 16 + (lane & 15);
        const float bj = biasall[colg];
        #pragma unroll
        for (int r = 0; r < 4; ++r) {
          const int row = bm + wm + i * 16 + (lane >> 4) * 4 + r;
          const float v = acc[i][j][r] + bj;
          oz[(size_t)row * DD + cj] = (_Float16)v;
          sv[i][r] += v;
          qv[i][r] += v * v;
        }
      }
    #pragma unroll
    for (int i = 0; i < 4; ++i)
      #pragma unroll
      for (int r = 0; r < 4; ++r) {
        float s = sv[i][r], q = qv[i][r];
        #pragma unroll
        for (int off = 1; off < 16; off <<= 1) { s += __shfl_xor(s, off); q += __shfl_xor(q, off); }
        if ((lane & 15) == 0) {
          const int row = bm + wm + i * 16 + (lane >> 4) * 4 + r;
          atomicAdd(&Srow[(size_t)z * NR + row], s);
          atomicAdd(&Qrow[(size_t)z * NR + row], q);
        }
      }
  }
}

// ---------------- loss ----------------

// Dtot[z][j] += sum_n |c[n+1,j]-c[n,j]| ; c = ov*S/max(|ov|*32*sqrt(Q),1e-8)
#define LCR 64
__global__ void losscol2_kernel(const _Float16* __restrict__ oh, const float* __restrict__ Srow,
                                const float* __restrict__ Qrow, float* __restrict__ Dtot) {
  const int z = blockIdx.y;
  const int n0 = blockIdx.x * LCR;
  int nend = n0 + LCR; if (nend > NR - 1) nend = NR - 1;
  const _Float16* base = oh + (size_t)z * NR * DD + (size_t)threadIdx.x * 4;
  const float* S = Srow + (size_t)z * NR;
  const float* Q = Qrow + (size_t)z * NR;
  float c[4], d[4] = {0.f, 0.f, 0.f, 0.f};
  auto compute = [&](int n, float* cv) {
    h4 o = *(const h4*)(base + (size_t)n * DD);
    float s = S[n];
    float t = 32.0f * sqrtf(Q[n]);
    #pragma unroll
    for (int k = 0; k < 4; ++k) {
      float ov = (float)o[k];
      cv[k] = ov * s / fmaxf(fabsf(ov) * t, 1e-8f);
    }
  };
  compute(n0, c);
  for (int n = n0 + 1; n <= nend; ++n) {
    float cn[4];
    compute(n, cn);
    #pragma unroll
    for (int k = 0; k < 4; ++k) { d[k] += fabsf(cn[k] - c[k]); c[k] = cn[k]; }
  }
  #pragma unroll
  for (int k = 0; k < 4; ++k) atomicAdd(&Dtot[z * DD + threadIdx.x * 4 + k], d[k]);
}

__global__ void writeloss_kernel(const float* __restrict__ Dtot, float* __restrict__ out) {
  int idx = blockIdx.x * 256 + threadIdx.x;
  int j = idx & (DD - 1);
  out[idx] = Dtot[j] + Dtot[DD + j] + Dtot[2 * DD + j] + Dtot[3 * DD + j] + Dtot[4 * DD + j];
}

// ---------------- launch ----------------

extern "C" void kernel_launch(void* const* d_in, const int* in_sizes, int n_in,
                              void* d_out, int out_size, void* d_ws, size_t ws_size,
                              hipStream_t stream) {
  const float* x      = (const float*)d_in[0];
  const float* fc1_W  = (const float*)d_in[1];
  const float* fc1_b  = (const float*)d_in[2];
  const float* fc2_W  = (const float*)d_in[3];
  const float* fc2_b  = (const float*)d_in[4];
  const float* comp_W = (const float*)d_in[5];
  const float* comp_b = (const float*)d_in[6];

  float* invtot  = (float*)d_out;
  float* nxtf    = invtot + (size_t)NR * DD;
  float* lossout = invtot + (size_t)2 * NR * DD;

  char* w = (char*)d_ws;
  auto alloc = [&](size_t bytes) { char* p = w; w += (bytes + 255) & ~(size_t)255; return p; };
  bf16* x_bf     = (bf16*)alloc((size_t)NR * DD * 2);          // 16 MB
  bf16* fc1T_bf  = (bf16*)alloc((size_t)DD * HH * 2);          // 8 MB
  bf16* fc2_bf   = (bf16*)alloc((size_t)DD * HH * 2);          // 8 MB
  bf16* compW_bf = (bf16*)alloc((size_t)NL * MSZ * 2);         // 10 MB
  bf16* M_bf     = (bf16*)alloc((size_t)MSZ * 2);              // 2 MB
  bf16* Mt_bf    = (bf16*)alloc((size_t)MSZ * 2);              // 2 MB
  bf16* Tt_buf   = (bf16*)alloc((size_t)2 * MSZ * 2);          // [Tt, T2t] 4 MB
  bf16* Pw       = (bf16*)alloc((size_t)4 * MSZ * 2);          // [T, T2, T3, T4] 8 MB
  bf16* S_bf     = (bf16*)alloc((size_t)MSZ * 2);              // 2 MB
  bf16* Gt       = (bf16*)alloc((size_t)NL * MSZ * 2);         // 10 MB
  bf16* Bbig     = (bf16*)alloc((size_t)6 * MSZ * 2);          // 12 MB
  _Float16* out_h = (_Float16*)alloc((size_t)NL * NR * DD * 2); // 80 MB
  float* cvec    = (float*)alloc(DD * 4);
  float* ebuf    = (float*)alloc((size_t)4 * DD * 4);
  float* biasall = (float*)alloc((size_t)6 * DD * 4);
  float* stats   = (float*)alloc((size_t)(NL * DD + 2 * NL * NR) * 4);
  float* Dtot = stats;
  float* Srow = stats + NL * DD;
  float* Qrow = Srow + (size_t)NL * NR;
  // split-K fp32 partials (16 MB) alias out_h: consumed by mbuild before gemm_main writes out_h
  float* Cp = (float*)out_h;
  (void)ws_size; (void)in_sizes; (void)n_in; (void)out_size;

  // conversions + zeros
  cvt_bf16_kernel<<<2048, 256, 0, stream>>>(x, x_bf, NR * DD / 4);
  cvt_bf16_kernel<<<1024, 256, 0, stream>>>(fc2_W, fc2_bf, DD * HH / 4);
  cvt_bf16_kernel<<<1024, 256, 0, stream>>>(comp_W, compW_bf, NL * MSZ / 4);
  transpose_cvt_kernel<<<dim3(DD / 64, HH / 64), 256, 0, stream>>>(fc1_W, fc1T_bf);
  cvec_kernel<<<DD, 256, 0, stream>>>(fc1_b, fc2_W, fc2_b, cvec);
  zero_kernel<<<(NL * DD + 2 * NL * NR + 255) / 256, 256, 0, stream>>>(stats, NL * DD + 2 * NL * NR);

  // M = fc1^T fc2^T (K=4096) via split-K(4) -> combine into M/Mt/T/Tt
  gemm_splitk<<<dim3(8, 8, 4), 256, 0, stream>>>(fc1T_bf, fc2_bf, Cp);
  mbuild_kernel<<<dim3(16, 16), 256, 0, stream>>>(Cp, M_bf, Mt_bf, Pw, Tt_buf);
  // G_i^T = compW_i * M^T (batched 5)
  gemm_b4<<<dim3(8, 8, NL), 256, 0, stream>>>(compW_bf, MSZ, M_bf, 0, Gt, MSZ,
                                              nullptr, nullptr, nullptr, 99);
  // Bout_1^T = G_1^T
  hipMemcpyAsync(Bbig + MSZ, Gt, (size_t)MSZ * 2, hipMemcpyDeviceToDevice, stream);
  // T2 (dual layout)
  gemm_dual<<<dim3(8, 8), 256, 0, stream>>>(Pw, Tt_buf, Tt_buf + MSZ, Pw + MSZ);
  // T3 = T2*T, T4 = T2*T2
  gemm_b4<<<dim3(8, 8, 2), 256, 0, stream>>>(Pw + MSZ, 0, Tt_buf, MSZ, Pw + 2 * MSZ, MSZ,
                                             nullptr, nullptr, nullptr, 99);
  // S = I+T+T2+T3+T4
  sbuild_kernel<<<MSZ / 256, 256, 0, stream>>>(Pw, S_bf);
  // Bout_i^T (i=2..5) + (S*M)^T
  gemm_b4<<<dim3(8, 8, NL), 256, 0, stream>>>(Gt + MSZ, MSZ, Pw, MSZ, Bbig + 2 * MSZ, MSZ,
                                              Mt_bf, S_bf, Bbig, 4);
  // bias vectors
  vecmat_kernel<<<dim3(DD, 2), 256, 0, stream>>>(cvec, Tt_buf, ebuf);
  vecmat_kernel<<<dim3(DD, 2), 256, 0, stream>>>(ebuf + DD, Tt_buf, ebuf + 2 * DD);
  biasall_kernel<<<dim3(DD, 6), 256, 0, stream>>>(cvec, ebuf, comp_W, comp_b, biasall);

  // main GEMM
  gemm_main<<<dim3(6 * DD / 128, NR / 128), 256, 0, stream>>>(
      x_bf, Bbig, biasall, x, invtot, nxtf, out_h, Srow, Qrow);

  // loss
  losscol2_kernel<<<dim3(NR / LCR, NL), 256, 0, stream>>>(out_h, Srow, Qrow, Dtot);
  writeloss_kernel<<<MSZ / 256, 256, 0, stream>>>(Dtot, lossout);
}